// Round 1
// baseline (500.463 us; speedup 1.0000x reference)
//
#include <hip/hip_runtime.h>

#define BATCH 4
#define NPTS 16384
#define MPTS 16384
#define NH 32
#define NK 15
#define NF 64
#define NC 64
#define MT 16   // output points per block

__global__ __launch_bounds__(256, 3) void kpconv_kernel(
    const float* __restrict__ points,     // [B,N,3]
    const float* __restrict__ features,   // [B,N,F]
    const float* __restrict__ outpts,     // [B,M,3]
    const float* __restrict__ kpts,       // [K,3]
    const float* __restrict__ kvals,      // [K,F,C]
    const int*   __restrict__ nbr,        // [B,M,H]
    float* __restrict__ out)              // [B,M,C]
{
    __shared__ float kp_s[48];                       // k_points (45 used)
    __shared__ float opt_s[MT * 3];                  // output points for this tile
    __shared__ float wf_s[8 * MT * 64];              // [j][p][f'] 32 KB, f' = (f+4p)&63
    __shared__ __align__(16) float scratch[2048];    // w: [0..1023], idx: [1024..1151]; red reuses all

    float* w_s = scratch;                            // [4 pl][32 h][8 j]
    int* idx_s = (int*)(scratch + 1024);             // [4 pl][32 h]

    const int tid   = threadIdx.x;
    const int batch = blockIdx.x >> 10;
    const int m0    = (blockIdx.x & 1023) << 4;

    if (tid < 45) kp_s[tid] = kpts[tid];
    if (tid >= 64 && tid < 64 + MT * 3)
        opt_s[tid - 64] = outpts[(size_t)(batch * MPTS + m0) * 3 + (tid - 64)];
    __syncthreads();

    const int g    = tid >> 6;   // wave id = group
    const int lane = tid & 63;
    const int pq   = lane >> 4;  // 0..3
    const int cq   = lane & 15;  // 0..15

    float acc[4][4];
    #pragma unroll
    for (int i = 0; i < 4; i++)
        #pragma unroll
        for (int j = 0; j < 4; j++) acc[i][j] = 0.f;

    #pragma unroll
    for (int half = 0; half < 2; half++) {
        const int k0 = half * 8;
        const int nk = half ? 7 : 8;

        // ---------------- stage A: build wf_s for k = k0 .. k0+nk-1 ----------------
        for (int s = 0; s < 4; s++) {
            // part 1: weights w[h][k] for 4 points (threads 0..127)
            if (tid < 128) {
                const int pl = tid >> 5, h = tid & 31;
                const int p  = s * 4 + pl;
                const int id = nbr[((size_t)(batch * MPTS + m0 + p)) * NH + h];
                idx_s[pl * 32 + h] = id;
                const size_t pbase = (size_t)(batch * NPTS + id) * 3;
                const float rx = points[pbase + 0] - opt_s[p * 3 + 0];
                const float ry = points[pbase + 1] - opt_s[p * 3 + 1];
                const float rz = points[pbase + 2] - opt_s[p * 3 + 2];
                float wv[8];
                #pragma unroll
                for (int j = 0; j < 8; j++) {
                    const int k = k0 + j;
                    float w = 0.f;
                    if (k < NK) {
                        const float dx = rx - kp_s[k * 3 + 0];
                        const float dy = ry - kp_s[k * 3 + 1];
                        const float dz = rz - kp_s[k * 3 + 2];
                        const float d  = sqrtf(dx * dx + dy * dy + dz * dz);
                        w = fmaxf(1.f - d, 0.f);   // EXTENT = 1.0
                    }
                    wv[j] = w;
                }
                float4* wd = (float4*)&w_s[(pl * 32 + h) * 8];
                wd[0] = make_float4(wv[0], wv[1], wv[2], wv[3]);
                wd[1] = make_float4(wv[4], wv[5], wv[6], wv[7]);
            }
            __syncthreads();

            // part 2: wf[j][p][f] accumulate (wave g handles point s*4+g, lane = f)
            {
                const int p = s * 4 + g;
                const int f = lane;
                float a[8] = {0.f, 0.f, 0.f, 0.f, 0.f, 0.f, 0.f, 0.f};
                const float4* w4 = (const float4*)&w_s[g * 32 * 8];
                const float* fbase = features + (size_t)(batch * NPTS) * NF + f;
                #pragma unroll 4
                for (int h = 0; h < NH; h++) {
                    const int id = idx_s[g * 32 + h];
                    const float fv = fbase[(size_t)id * NF];
                    const float4 w0 = w4[h * 2 + 0];
                    const float4 w1 = w4[h * 2 + 1];
                    a[0] = fmaf(w0.x, fv, a[0]);
                    a[1] = fmaf(w0.y, fv, a[1]);
                    a[2] = fmaf(w0.z, fv, a[2]);
                    a[3] = fmaf(w0.w, fv, a[3]);
                    a[4] = fmaf(w1.x, fv, a[4]);
                    a[5] = fmaf(w1.y, fv, a[5]);
                    a[6] = fmaf(w1.z, fv, a[6]);
                    a[7] = fmaf(w1.w, fv, a[7]);
                }
                const int fp = (f + 4 * p) & 63;
                #pragma unroll
                for (int j = 0; j < 8; j++) wf_s[(j * MT + p) * 64 + fp] = a[j];
            }
            __syncthreads();
        }

        // ---------------- stage B: acc += wf[:,kslice,:] @ V[kslice] ----------------
        // wave g handles f in [g*16, g*16+16); thread tile 4p x 4c
        for (int j = 0; j < nk; j++) {
            const int k = k0 + j;
            #pragma unroll
            for (int fi = 0; fi < 16; fi++) {
                const int f = g * 16 + fi;
                const float4 vv = *(const float4*)&kvals[((size_t)(k * NF + f)) * NC + cq * 4];
                #pragma unroll
                for (int pi = 0; pi < 4; pi++) {
                    const int p = pq * 4 + pi;
                    const float wp = wf_s[(j * MT + p) * 64 + ((f + 4 * p) & 63)];
                    acc[pi][0] = fmaf(wp, vv.x, acc[pi][0]);
                    acc[pi][1] = fmaf(wp, vv.y, acc[pi][1]);
                    acc[pi][2] = fmaf(wp, vv.z, acc[pi][2]);
                    acc[pi][3] = fmaf(wp, vv.w, acc[pi][3]);
                }
            }
        }
        __syncthreads();   // wf_s / w_s reused next half (or scratch reused below)
    }

    // ---------------- reduce partial sums across the 4 waves ----------------
    float4* red4 = (float4*)scratch;   // 512 float4 = whole scratch (w_s/idx_s dead)
    if (g & 1) {                       // waves 1,3 write
        const int r = g >> 1;
        #pragma unroll
        for (int pi = 0; pi < 4; pi++)
            red4[(r * MT + pq * 4 + pi) * 16 + cq] =
                make_float4(acc[pi][0], acc[pi][1], acc[pi][2], acc[pi][3]);
    }
    __syncthreads();
    if (!(g & 1)) {                    // waves 0,2 add partner
        const int r = g >> 1;
        #pragma unroll
        for (int pi = 0; pi < 4; pi++) {
            const float4 v = red4[(r * MT + pq * 4 + pi) * 16 + cq];
            acc[pi][0] += v.x; acc[pi][1] += v.y; acc[pi][2] += v.z; acc[pi][3] += v.w;
        }
    }
    __syncthreads();
    if (g == 2) {                      // wave 2 writes
        #pragma unroll
        for (int pi = 0; pi < 4; pi++)
            red4[(pq * 4 + pi) * 16 + cq] =
                make_float4(acc[pi][0], acc[pi][1], acc[pi][2], acc[pi][3]);
    }
    __syncthreads();
    if (g == 0) {                      // wave 0 finalizes + stores
        #pragma unroll
        for (int pi = 0; pi < 4; pi++) {
            const float4 v = red4[(pq * 4 + pi) * 16 + cq];
            float4 o;
            o.x = acc[pi][0] + v.x;
            o.y = acc[pi][1] + v.y;
            o.z = acc[pi][2] + v.z;
            o.w = acc[pi][3] + v.w;
            *(float4*)&out[((size_t)(batch * MPTS + m0 + pq * 4 + pi)) * NC + cq * 4] = o;
        }
    }
}

extern "C" void kernel_launch(void* const* d_in, const int* in_sizes, int n_in,
                              void* d_out, int out_size, void* d_ws, size_t ws_size,
                              hipStream_t stream) {
    const float* points   = (const float*)d_in[0];
    const float* features = (const float*)d_in[1];
    const float* outpts   = (const float*)d_in[2];
    const float* kpts     = (const float*)d_in[3];
    const float* kvals    = (const float*)d_in[4];
    const int*   nbr      = (const int*)d_in[5];
    float* out = (float*)d_out;

    const int blocks = BATCH * (MPTS / MT);   // 4096
    kpconv_kernel<<<blocks, 256, 0, stream>>>(points, features, outpts, kpts, kvals, nbr, out);
}

// Round 2
// 159.876 us; speedup vs baseline: 3.1303x; 3.1303x over previous
//
#include <hip/hip_runtime.h>

#define BATCH 4
#define NPTS 16384
#define MPTS 16384
#define NH 32
#define NK 15
#define NF 64
#define NC 64
#define MT 16

typedef short short8 __attribute__((ext_vector_type(8)));
typedef float floatx4 __attribute__((ext_vector_type(4)));

__device__ __forceinline__ unsigned short f2bf(float x) {
    unsigned int u = __builtin_bit_cast(unsigned int, x);
    u = u + 0x7FFFu + ((u >> 16) & 1u);   // RNE
    return (unsigned short)(u >> 16);
}

// ---------- prep 1: features fp32 -> bf16 (ws) ----------
__global__ void feat_cvt_kernel(const float* __restrict__ src, unsigned short* __restrict__ dst) {
    const int gid = blockIdx.x * 256 + threadIdx.x;        // 524288 threads x 8 elems
    const size_t base = (size_t)gid * 8;
    float4 a = *(const float4*)(src + base);
    float4 b = *(const float4*)(src + base + 4);
    uint4 o;
    o.x = (unsigned)f2bf(a.x) | ((unsigned)f2bf(a.y) << 16);
    o.y = (unsigned)f2bf(a.z) | ((unsigned)f2bf(a.w) << 16);
    o.z = (unsigned)f2bf(b.x) | ((unsigned)f2bf(b.y) << 16);
    o.w = (unsigned)f2bf(b.z) | ((unsigned)f2bf(b.w) << 16);
    *(uint4*)(dst + base) = o;
}

// ---------- prep 2: k_values -> bf16 in B-fragment order ----------
// kappa = f*16 + k (k padded to 16, zero for k==15). KF = 1024 -> 32 mfma steps.
// Vp[((kk*4 + ct)*64 + lane)*8 + j] = V[kappa = kk*32 + (lane>>4)*8 + j][c = ct*16 + (lane&15)]
__global__ void vprep_kernel(const float* __restrict__ kv, unsigned short* __restrict__ vp) {
    const int gid = blockIdx.x * 256 + threadIdx.x;        // 8192 threads
    const int lane = gid & 63;
    const int ct   = (gid >> 6) & 3;
    const int kk   = gid >> 8;                             // 0..31
    const int c    = ct * 16 + (lane & 15);
    const int kap0 = kk * 32 + (lane >> 4) * 8;
    unsigned int o[4];
    #pragma unroll
    for (int jj = 0; jj < 4; jj++) {
        unsigned short lo, hi;
        {
            const int kap = kap0 + jj * 2;
            const int f = kap >> 4, k = kap & 15;
            lo = (k < NK) ? f2bf(kv[((size_t)(k * NF + f)) * NC + c]) : (unsigned short)0;
        }
        {
            const int kap = kap0 + jj * 2 + 1;
            const int f = kap >> 4, k = kap & 15;
            hi = (k < NK) ? f2bf(kv[((size_t)(k * NF + f)) * NC + c]) : (unsigned short)0;
        }
        o[jj] = (unsigned)lo | ((unsigned)hi << 16);
    }
    *(uint4*)(vp + (size_t)gid * 8) = make_uint4(o[0], o[1], o[2], o[3]);
}

// ---------- main kernel ----------
__global__ __launch_bounds__(256, 3) void kpconv_kernel(
    const float* __restrict__ points,          // [B,N,3]
    const unsigned short* __restrict__ featbf, // [B,N,F] bf16 (ws)
    const float* __restrict__ outpts,          // [B,M,3]
    const float* __restrict__ kpts,            // [K,3]
    const unsigned short* __restrict__ vp,     // B-frag-ordered V bf16 (ws)
    const int*   __restrict__ nbr,             // [B,M,H]
    float* __restrict__ out)                   // [B,M,C]
{
    __shared__ unsigned short wf_s[MT * 1032];     // [p][f*16+k], p-stride 1032 (pad) = 33024 B
    __shared__ unsigned short feat_s[4 * 32 * 36]; // [pl][h][f_local 36]           =  9216 B
    __shared__ unsigned short w_s[4 * 16 * 40];    // [pl][k][h 40]                 =  5120 B
    __shared__ int   idx_s[MT * 32];               //                                  2048 B
    __shared__ float kp_s[48];

    const int tid   = threadIdx.x;
    const int batch = blockIdx.x >> 10;
    const int m0    = (blockIdx.x & 1023) << 4;

    if (tid < 45) kp_s[tid] = kpts[tid];
    {
        const size_t nb = (size_t)(batch * MPTS + m0) * NH;
        idx_s[tid]       = nbr[nb + tid];
        idx_s[256 + tid] = nbr[nb + 256 + tid];
    }
    __syncthreads();

    const int g    = tid >> 6;    // wave id
    const int lane = tid & 63;
    const int cl   = lane & 15;
    const int q    = lane >> 4;

    for (int r = 0; r < 4; r++) {
        // ---- step B: compute w (all 256 threads) + stage feat half 0 ----
        {
            const int pl = tid >> 6;
            const int h  = tid & 31;
            const int ktop = (tid >> 5) & 1;
            const int p  = r * 4 + pl;
            const int id = idx_s[p * 32 + h];
            const size_t pb = ((size_t)(batch * NPTS) + id) * 3;
            const size_t ob = (size_t)(batch * MPTS + m0 + p) * 3;
            const float rx = points[pb + 0] - outpts[ob + 0];
            const float ry = points[pb + 1] - outpts[ob + 1];
            const float rz = points[pb + 2] - outpts[ob + 2];
            #pragma unroll
            for (int kk2 = 0; kk2 < 8; kk2++) {
                const int k = ktop * 8 + kk2;
                float w = 0.f;
                if (k < NK) {
                    const float dx = rx - kp_s[k * 3 + 0];
                    const float dy = ry - kp_s[k * 3 + 1];
                    const float dz = rz - kp_s[k * 3 + 2];
                    const float d  = sqrtf(dx * dx + dy * dy + dz * dz);
                    w = fmaxf(1.f - d, 0.f);
                }
                w_s[(pl * 16 + k) * 40 + h] = f2bf(w);
            }
        }
        {   // stage features f in [0,32): 2 threads/row, 16 elems each
            const int rowId = tid >> 1, qh = tid & 1;
            const int pl = rowId >> 5, h = rowId & 31;
            const int id = idx_s[(r * 4 + pl) * 32 + h];
            const unsigned short* src = featbf + ((size_t)(batch * NPTS) + id) * NF;
            unsigned short* dsth = &feat_s[(pl * 32 + h) * 36];
            #pragma unroll
            for (int cch = 0; cch < 2; cch++) {
                const int off = qh * 8 + cch * 16;       // elements
                uint4 d = *(const uint4*)(src + off);
                *(uint2*)(dsth + off)     = make_uint2(d.x, d.y);
                *(uint2*)(dsth + off + 4) = make_uint2(d.z, d.w);
            }
        }
        __syncthreads();

        // A-frag (w) for this round's point — same for all 4 f-tiles
        const int p = r * 4 + g;
        const uint4 ua = *(const uint4*)&w_s[(g * 16 + cl) * 40 + q * 8];
        const short8 af = __builtin_bit_cast(short8, ua);

        // ---- step C: einsum1 f-tiles 0,1 (f_local 0..31) ----
        #pragma unroll
        for (int t = 0; t < 2; t++) {
            const int fl = t * 16 + cl;
            const int fb = (g * 32 + q * 8) * 36 + fl;
            short8 bfv;
            #pragma unroll
            for (int j = 0; j < 8; j++) bfv[j] = (short)feat_s[fb + j * 36];
            floatx4 d = {0.f, 0.f, 0.f, 0.f};
            d = __builtin_amdgcn_mfma_f32_16x16x32_bf16(af, bfv, d, 0, 0, 0);
            const unsigned int lo = (unsigned)f2bf(d[0]) | ((unsigned)f2bf(d[1]) << 16);
            const unsigned int hi = (unsigned)f2bf(d[2]) | ((unsigned)f2bf(d[3]) << 16);
            *(uint2*)&wf_s[p * 1032 + (t * 16 + cl) * 16 + q * 4] = make_uint2(lo, hi);
        }
        __syncthreads();

        // ---- step D: stage feat half 1 (f in [32,64)) ----
        {
            const int rowId = tid >> 1, qh = tid & 1;
            const int pl = rowId >> 5, h = rowId & 31;
            const int id = idx_s[(r * 4 + pl) * 32 + h];
            const unsigned short* src = featbf + ((size_t)(batch * NPTS) + id) * NF + 32;
            unsigned short* dsth = &feat_s[(pl * 32 + h) * 36];
            #pragma unroll
            for (int cch = 0; cch < 2; cch++) {
                const int off = qh * 8 + cch * 16;
                uint4 d = *(const uint4*)(src + off);
                *(uint2*)(dsth + off)     = make_uint2(d.x, d.y);
                *(uint2*)(dsth + off + 4) = make_uint2(d.z, d.w);
            }
        }
        __syncthreads();

        // ---- step E: einsum1 f-tiles 2,3 (f_local 0..31 = global f-32) ----
        #pragma unroll
        for (int t = 0; t < 2; t++) {
            const int fl = t * 16 + cl;
            const int fb = (g * 32 + q * 8) * 36 + fl;
            short8 bfv;
            #pragma unroll
            for (int j = 0; j < 8; j++) bfv[j] = (short)feat_s[fb + j * 36];
            floatx4 d = {0.f, 0.f, 0.f, 0.f};
            d = __builtin_amdgcn_mfma_f32_16x16x32_bf16(af, bfv, d, 0, 0, 0);
            const unsigned int lo = (unsigned)f2bf(d[0]) | ((unsigned)f2bf(d[1]) << 16);
            const unsigned int hi = (unsigned)f2bf(d[2]) | ((unsigned)f2bf(d[3]) << 16);
            *(uint2*)&wf_s[p * 1032 + ((2 + t) * 16 + cl) * 16 + q * 4] = make_uint2(lo, hi);
        }
        __syncthreads();
    }

    // ---- einsum2: out[p, c] = sum_kappa wf[p,kappa] * V[kappa,c]; wave g -> c-tile g ----
    floatx4 acc = {0.f, 0.f, 0.f, 0.f};
    #pragma unroll 8
    for (int kk = 0; kk < 32; kk++) {
        const uint4 uA = *(const uint4*)&wf_s[cl * 1032 + kk * 32 + q * 8];
        const uint4 uB = *(const uint4*)(vp + ((size_t)((kk * 4 + g) * 64 + lane)) * 8);
        acc = __builtin_amdgcn_mfma_f32_16x16x32_bf16(
            __builtin_bit_cast(short8, uA), __builtin_bit_cast(short8, uB), acc, 0, 0, 0);
    }

    // D: row = q*4+ri = p, col = cl = c within tile g
    #pragma unroll
    for (int ri = 0; ri < 4; ri++) {
        out[((size_t)(batch * MPTS + m0 + q * 4 + ri)) * NC + g * 16 + cl] = acc[ri];
    }
}

extern "C" void kernel_launch(void* const* d_in, const int* in_sizes, int n_in,
                              void* d_out, int out_size, void* d_ws, size_t ws_size,
                              hipStream_t stream) {
    const float* points   = (const float*)d_in[0];
    const float* features = (const float*)d_in[1];
    const float* outpts   = (const float*)d_in[2];
    const float* kpts     = (const float*)d_in[3];
    const float* kvals    = (const float*)d_in[4];
    const int*   nbr      = (const int*)d_in[5];
    float* out = (float*)d_out;

    unsigned short* vp     = (unsigned short*)d_ws;                 // 131072 B
    unsigned short* featbf = (unsigned short*)((char*)d_ws + 131072); // 8 MB

    vprep_kernel<<<32, 256, 0, stream>>>(kvals, vp);
    feat_cvt_kernel<<<2048, 256, 0, stream>>>(features, featbf);

    const int blocks = BATCH * (MPTS / MT);   // 4096
    kpconv_kernel<<<blocks, 256, 0, stream>>>(points, featbf, outpts, kpts, vp, nbr, out);
}